// Round 7
// baseline (872.022 us; speedup 1.0000x reference)
//
#include <hip/hip_runtime.h>

#define TT 2048
#define BB 256
#define XX 64
#define HH 128
#define YY 32
#define SSTR 12           // 8 data + 4 pad floats per kg-slice (2-way banks = free)
#define HBUF (16 * SSTR)  // 192 floats per h buffer

// 512 threads = 8 waves = 2 waves/SIMD.  J=4 outputs/thread, Kg=16 k-groups.
// kg = lane&15 (h[8kg..+7], x[4kg..+3]); jg = w*4 + (lane>>4); j = 4jg..4jg+3.
// Reduction over kg bits {0,1,2,3}: xor1+xor2 (quad_perm, exact) then
// row_half_mirror (i<->7-i, exact xor4 AFTER quads uniform; involution =>
// direction-proof) then row_ror:8 (= xor8, direction-agnostic).  All VALU.
// Weights (48 floats, pre-scaled by 2*log2(e)) pinned in registers;
// waves_per_eu(2,2) pins the allocator budget at 256 VGPRs (R6: launch_bounds
// min-arg alone let the allocator shrink to 48 and remat weight loads from L2
// every step).  h in padded LDS; x direct from global, prefetched 1 step.
// R3: bias after reduction | R5: never use row_ror:4 as xor4.

typedef float v2f __attribute__((ext_vector_type(2)));
typedef float v4f __attribute__((ext_vector_type(4)));

#define PKFMA(acc, a, b)                                              \
    asm("v_pk_fma_f32 %0, %1, %2, %0 op_sel:[0,0,0] op_sel_hi:[1,1,1]"\
        : "+v"(acc) : "v"(a), "v"(b))

template<int CTRL>
static __device__ __forceinline__ float dpp_add(float s) {
    const int t = __builtin_amdgcn_update_dpp(
        0, __float_as_int(s), CTRL, 0xF, 0xF, true);
    return s + __int_as_float(t);
}

static __device__ __forceinline__ void pin2(v2f& v) {
    asm volatile("" : "+v"(v));
}

#define LO2(v) __builtin_shufflevector(v, v, 0, 1)
#define HI2(v) __builtin_shufflevector(v, v, 2, 3)

__global__ __launch_bounds__(512)
__attribute__((amdgpu_waves_per_eu(2, 2)))
void rnn_persist_kernel(const float* __restrict__ x,
                        const float* __restrict__ W_ih,
                        const float* __restrict__ W_hh,
                        const float* __restrict__ b_ih,
                        const float* __restrict__ b_hh,
                        const float* __restrict__ W_out,
                        const float* __restrict__ b_out,
                        float* __restrict__ out)
{
    __shared__ __align__(16) float h_lds[2][HBUF];

    const int tid  = threadIdx.x;
    const int b    = blockIdx.x;
    const int w    = tid >> 6;            // 0..7
    const int lane = tid & 63;
    const int kg   = lane & 15;           // k-group on lane bits {0,1,2,3}
    const int jg   = w * 4 + (lane >> 4); // 0..31
    const int j0   = jg * 4;              // 0..124

    const float SC = 2.8853900817779268f;  // 2*log2(e): prescale, exp2 direct

    // ---- weights into registers (48 floats, prescaled), pinned ----
    v2f whh2[4][4];   // 4 j x 8 floats of W_hh k-slice
    v2f wih2[4][2];   // 4 j x 4 floats of W_ih k-slice
    float bs[4];
    #pragma unroll
    for (int jj = 0; jj < 4; ++jj) {
        const v2f* ph = (const v2f*)(W_hh + (j0 + jj) * HH + kg * 8);
        #pragma unroll
        for (int c = 0; c < 4; ++c) whh2[jj][c] = ph[c] * SC;
        const v2f* pi = (const v2f*)(W_ih + (j0 + jj) * XX + kg * 4);
        #pragma unroll
        for (int c = 0; c < 2; ++c) wih2[jj][c] = pi[c] * SC;
        bs[jj] = (b_ih[j0 + jj] + b_hh[j0 + jj]) * SC;
    }
    #pragma unroll
    for (int jj = 0; jj < 4; ++jj) {
        #pragma unroll
        for (int c = 0; c < 4; ++c) pin2(whh2[jj][c]);
        pin2(wih2[jj][0]); pin2(wih2[jj][1]);
    }

    const float* xg = x + (size_t)b * TT * XX + kg * 4;
    v4f xc = *(const v4f*)xg;

    if (tid < HBUF) h_lds[0][tid] = 0.f;
    __syncthreads();

    const int woff = (j0 >> 3) * SSTR + (j0 & 7);  // writer slot (kg==0)

    int par = 0;
    #pragma unroll 2
    for (int t = 0; t < TT; ++t) {
        // prefetch x for t+1 (VMEM pipe, hidden under compute)
        const int tn = (t < TT - 1) ? t + 1 : t;
        v4f xn = *(const v4f*)(xg + (size_t)tn * XX);

        // h slice: 2 x b128 broadcast reads (padded stride -> <=2-way = free)
        const v4f* hp = (const v4f*)&h_lds[par][kg * SSTR];
        const v4f H0 = hp[0], H1 = hp[1];
        const v2f h2[4] = { LO2(H0), HI2(H0), LO2(H1), HI2(H1) };
        const v2f x2[2] = { LO2(xc), HI2(xc) };

        float hn[4];
        #pragma unroll
        for (int jj = 0; jj < 4; ++jj) {
            v2f a = {0.f, 0.f}, c = {0.f, 0.f};
            PKFMA(a, wih2[jj][0], x2[0]); PKFMA(c, wih2[jj][1], x2[1]);
            PKFMA(a, whh2[jj][0], h2[0]); PKFMA(c, whh2[jj][1], h2[1]);
            PKFMA(a, whh2[jj][2], h2[2]); PKFMA(c, whh2[jj][3], h2[3]);
            a = a + c;                       // v_pk_add_f32
            float s = a.x + a.y;
            s = dpp_add<0xB1>(s);    // quad_perm [1,0,3,2]  = xor1 (exact)
            s = dpp_add<0x4E>(s);    // quad_perm [2,3,0,1]  = xor2 (exact)
            s = dpp_add<0x141>(s);   // row_half_mirror      = xor4 (quads uniform)
            s = dpp_add<0x128>(s);   // row_ror:8            = xor8 (dir-agnostic)
            s += bs[jj];             // bias AFTER reduction (R3), prescaled
            const float e = __builtin_amdgcn_exp2f(s);
            hn[jj] = fmaf(-2.f, __builtin_amdgcn_rcpf(e + 1.f), 1.f);
        }

        if (kg == 0) {
            v4f hw = { hn[0], hn[1], hn[2], hn[3] };
            *(v4f*)&h_lds[par ^ 1][woff] = hw;
        }
        __syncthreads();
        par ^= 1;
        xc = xn;
    }

    // ---- readout: out[b, :] = h_last @ W_out^T + b_out ----
    if (tid < YY) {
        const float* h  = h_lds[par];
        const float* wr = W_out + tid * HH;
        float r0 = 0.f, r1 = 0.f, r2 = 0.f, r3 = 0.f;
        #pragma unroll
        for (int s16 = 0; s16 < 16; ++s16) {   // 16 slices of 8 floats
            #pragma unroll
            for (int c = 0; c < 2; ++c) {
                const float4 wv = *(const float4*)(wr + s16 * 8 + c * 4);
                const float4 hv = *(const float4*)(h + s16 * SSTR + c * 4);
                r0 = fmaf(wv.x, hv.x, r0); r1 = fmaf(wv.y, hv.y, r1);
                r2 = fmaf(wv.z, hv.z, r2); r3 = fmaf(wv.w, hv.w, r3);
            }
        }
        out[b * YY + tid] = b_out[tid] + ((r0 + r1) + (r2 + r3));
    }
}

extern "C" void kernel_launch(void* const* d_in, const int* in_sizes, int n_in,
                              void* d_out, int out_size, void* d_ws, size_t ws_size,
                              hipStream_t stream) {
    const float* x     = (const float*)d_in[0];
    const float* W_ih  = (const float*)d_in[1];
    const float* W_hh  = (const float*)d_in[2];
    const float* b_ih  = (const float*)d_in[3];
    const float* b_hh  = (const float*)d_in[4];
    const float* W_out = (const float*)d_in[5];
    const float* b_out = (const float*)d_in[6];
    float* out = (float*)d_out;

    rnn_persist_kernel<<<BB, 512, 0, stream>>>(x, W_ih, W_hh, b_ih, b_hh,
                                               W_out, b_out, out);
}

// Round 8
// 869.028 us; speedup vs baseline: 1.0034x; 1.0034x over previous
//
#include <hip/hip_runtime.h>

#define TT 2048
#define BB 256
#define XX 64
#define HH 128
#define YY 32
#define SSTR 12           // 8 data + 4 pad floats per kg-slice
#define HBUF (16 * SSTR)  // 192 floats per h buffer

// 1024 threads = 16 waves = 4 waves/SIMD.  J=2 outputs/thread, Kg=16.
// kg = lane&15 (h[8kg..+7], x[4kg..+3]); jg = w*4 + (lane>>4); j = 2jg,2jg+1.
// Wave w owns outputs [8w, 8w+8) -> writes its private LDS slice w.
// Reduction over kg bits {0..3}: xor1+xor2 (quad_perm, exact), xor4
// (row_half_mirror, involution), xor8 (row_ror:8, direction-agnostic).
// R7 lessons: v_pk_fma_f32 is HALF-RATE (157 TF spec = scalar rate) so pk
// only saves decode, not issue; 2 waves/SIMD left 31% VALU idle -> 4 waves.
// R6: waves_per_eu exact pin, else allocator remats weights from L2.
// R3: bias after reduction | R5: never row_ror:4 as xor4.

typedef float v2f __attribute__((ext_vector_type(2)));
typedef float v4f __attribute__((ext_vector_type(4)));

#define PKFMA(acc, a, b)                                              \
    asm("v_pk_fma_f32 %0, %1, %2, %0 op_sel:[0,0,0] op_sel_hi:[1,1,1]"\
        : "+v"(acc) : "v"(a), "v"(b))

template<int CTRL>
static __device__ __forceinline__ float dpp_add(float s) {
    const int t = __builtin_amdgcn_update_dpp(
        0, __float_as_int(s), CTRL, 0xF, 0xF, true);
    return s + __int_as_float(t);
}

static __device__ __forceinline__ void pin2(v2f& v) {
    asm volatile("" : "+v"(v));
}

#define LO2(v) __builtin_shufflevector(v, v, 0, 1)
#define HI2(v) __builtin_shufflevector(v, v, 2, 3)

__global__ __launch_bounds__(1024)
__attribute__((amdgpu_waves_per_eu(4, 4)))
void rnn_persist_kernel(const float* __restrict__ x,
                        const float* __restrict__ W_ih,
                        const float* __restrict__ W_hh,
                        const float* __restrict__ b_ih,
                        const float* __restrict__ b_hh,
                        const float* __restrict__ W_out,
                        const float* __restrict__ b_out,
                        float* __restrict__ out)
{
    __shared__ __align__(16) float h_lds[2][HBUF];

    const int tid  = threadIdx.x;
    const int b    = blockIdx.x;
    const int w    = tid >> 6;            // 0..15
    const int lane = tid & 63;
    const int kg   = lane & 15;           // k-group on lane bits {0,1,2,3}
    const int jg   = w * 4 + (lane >> 4); // 0..63
    const int j0   = jg * 2;              // 0..126

    const float SC = 2.8853900817779268f;  // 2*log2(e): prescale, exp2 direct

    // ---- weights into registers (24 floats, prescaled), pinned ----
    v2f whh2[2][4];   // 2 j x 8 floats of W_hh k-slice
    v2f wih2[2][2];   // 2 j x 4 floats of W_ih k-slice
    float bs[2];
    #pragma unroll
    for (int jj = 0; jj < 2; ++jj) {
        const v2f* ph = (const v2f*)(W_hh + (j0 + jj) * HH + kg * 8);
        #pragma unroll
        for (int c = 0; c < 4; ++c) whh2[jj][c] = ph[c] * SC;
        const v2f* pi = (const v2f*)(W_ih + (j0 + jj) * XX + kg * 4);
        #pragma unroll
        for (int c = 0; c < 2; ++c) wih2[jj][c] = pi[c] * SC;
        bs[jj] = (b_ih[j0 + jj] + b_hh[j0 + jj]) * SC;
    }
    #pragma unroll
    for (int jj = 0; jj < 2; ++jj) {
        #pragma unroll
        for (int c = 0; c < 4; ++c) pin2(whh2[jj][c]);
        pin2(wih2[jj][0]); pin2(wih2[jj][1]);
    }

    const float* xg = x + (size_t)b * TT * XX + kg * 4;
    v4f xc = *(const v4f*)xg;

    if (tid < HBUF) h_lds[0][tid] = 0.f;
    __syncthreads();

    // writer slot (kg==0): wave w's slice, offset 2*(jg&3) within slice
    const int woff = w * SSTR + (j0 & 7);

    int par = 0;
    #pragma unroll 2
    for (int t = 0; t < TT; ++t) {
        // prefetch x for t+1 (VMEM pipe, hidden under compute)
        const int tn = (t < TT - 1) ? t + 1 : t;
        v4f xn = *(const v4f*)(xg + (size_t)tn * XX);

        // h slice: 2 x b128 broadcast reads
        const v4f* hp = (const v4f*)&h_lds[par][kg * SSTR];
        const v4f H0 = hp[0], H1 = hp[1];
        const v2f h2[4] = { LO2(H0), HI2(H0), LO2(H1), HI2(H1) };
        const v2f x2[2] = { LO2(xc), HI2(xc) };

        float hn[2];
        #pragma unroll
        for (int jj = 0; jj < 2; ++jj) {
            v2f a = {0.f, 0.f}, c = {0.f, 0.f};
            PKFMA(a, wih2[jj][0], x2[0]); PKFMA(c, wih2[jj][1], x2[1]);
            PKFMA(a, whh2[jj][0], h2[0]); PKFMA(c, whh2[jj][1], h2[1]);
            PKFMA(a, whh2[jj][2], h2[2]); PKFMA(c, whh2[jj][3], h2[3]);
            a = a + c;                       // v_pk_add_f32
            float s = a.x + a.y;
            s = dpp_add<0xB1>(s);    // quad_perm [1,0,3,2]  = xor1 (exact)
            s = dpp_add<0x4E>(s);    // quad_perm [2,3,0,1]  = xor2 (exact)
            s = dpp_add<0x141>(s);   // row_half_mirror      = xor4 (quads uniform)
            s = dpp_add<0x128>(s);   // row_ror:8            = xor8 (dir-agnostic)
            s += bs[jj];             // bias AFTER reduction (R3), prescaled
            const float e = __builtin_amdgcn_exp2f(s);
            hn[jj] = fmaf(-2.f, __builtin_amdgcn_rcpf(e + 1.f), 1.f);
        }

        if (kg == 0) {
            v2f hw = { hn[0], hn[1] };
            *(v2f*)&h_lds[par ^ 1][woff] = hw;
        }
        __syncthreads();
        par ^= 1;
        xc = xn;
    }

    // ---- readout: out[b, :] = h_last @ W_out^T + b_out ----
    if (tid < YY) {
        const float* h  = h_lds[par];
        const float* wr = W_out + tid * HH;
        float r0 = 0.f, r1 = 0.f, r2 = 0.f, r3 = 0.f;
        #pragma unroll
        for (int s16 = 0; s16 < 16; ++s16) {   // 16 slices of 8 floats
            #pragma unroll
            for (int c = 0; c < 2; ++c) {
                const float4 wv = *(const float4*)(wr + s16 * 8 + c * 4);
                const float4 hv = *(const float4*)(h + s16 * SSTR + c * 4);
                r0 = fmaf(wv.x, hv.x, r0); r1 = fmaf(wv.y, hv.y, r1);
                r2 = fmaf(wv.z, hv.z, r2); r3 = fmaf(wv.w, hv.w, r3);
            }
        }
        out[b * YY + tid] = b_out[tid] + ((r0 + r1) + (r2 + r3));
    }
}

extern "C" void kernel_launch(void* const* d_in, const int* in_sizes, int n_in,
                              void* d_out, int out_size, void* d_ws, size_t ws_size,
                              hipStream_t stream) {
    const float* x     = (const float*)d_in[0];
    const float* W_ih  = (const float*)d_in[1];
    const float* W_hh  = (const float*)d_in[2];
    const float* b_ih  = (const float*)d_in[3];
    const float* b_hh  = (const float*)d_in[4];
    const float* W_out = (const float*)d_in[5];
    const float* b_out = (const float*)d_in[6];
    float* out = (float*)d_out;

    rnn_persist_kernel<<<BB, 1024, 0, stream>>>(x, W_ih, W_hh, b_ih, b_hh,
                                                W_out, b_out, out);
}

// Round 9
// 590.002 us; speedup vs baseline: 1.4780x; 1.4729x over previous
//
#include <hip/hip_runtime.h>

#define TT 2048
#define BB 256
#define XX 64
#define HH 128
#define YY 32
#define SSTR 20          // 16 data + 4 pad floats per kg-slice
#define HBUF (8 * SSTR)  // 160 floats per h buffer

// 512 threads = 8 waves = 2 waves/SIMD.  J=2 outputs/thread, Kg=8 k-groups.
// kg on lane bits {0,1,3} (h[16kg..+16), x[8kg..+8)); jg on bits {2,4,5}.
// Reduce-scatter: merge the two per-output partials at stage 1 (cndmask pair
// + xor1), so each lane reduces ONE output (selected by lane bit0); stages
// xor2 (quad_perm) + xor8 (row_ror:8) preserve bit0.  ONE tanh tail per wave
// (was 2*J) -- R8 showed tails+butterfly (~1600 of 3360 cyc/CU-step) dwarf
// the 768-cyc MAC floor; tail instances = 2*Kg, so Kg: 16 -> 8.
// All exchanges direction-proof (R5: quad_perm exact; ror:8 = xor8).
// R6: waves_per_eu exact pin or allocator remats weights from L2.
// R3: bias after reduction (per-lane bsel).  R7: pk_fma is half-rate.

typedef float v2f __attribute__((ext_vector_type(2)));
typedef float v4f __attribute__((ext_vector_type(4)));

#define PKFMA(acc, a, b)                                              \
    asm("v_pk_fma_f32 %0, %1, %2, %0 op_sel:[0,0,0] op_sel_hi:[1,1,1]"\
        : "+v"(acc) : "v"(a), "v"(b))

template<int CTRL>
static __device__ __forceinline__ float dpp_mov(float s) {
    return __int_as_float(__builtin_amdgcn_update_dpp(
        0, __float_as_int(s), CTRL, 0xF, 0xF, true));
}

static __device__ __forceinline__ void pin2(v2f& v) {
    asm volatile("" : "+v"(v));
}

#define LO2(v) __builtin_shufflevector(v, v, 0, 1)
#define HI2(v) __builtin_shufflevector(v, v, 2, 3)

__global__ __launch_bounds__(512)
__attribute__((amdgpu_waves_per_eu(2, 2)))
void rnn_persist_kernel(const float* __restrict__ x,
                        const float* __restrict__ W_ih,
                        const float* __restrict__ W_hh,
                        const float* __restrict__ b_ih,
                        const float* __restrict__ b_hh,
                        const float* __restrict__ W_out,
                        const float* __restrict__ b_out,
                        float* __restrict__ out)
{
    __shared__ __align__(16) float h_lds[2][HBUF];

    const int tid  = threadIdx.x;
    const int b    = blockIdx.x;
    const int w    = tid >> 6;                                   // 0..7
    const int lane = tid & 63;
    const int kg   = (lane & 3) | ((lane >> 1) & 4);             // bits 0,1,3
    const int jgl  = ((lane >> 2) & 1) | (((lane >> 4) & 3) << 1);
    const int jg   = w * 8 + jgl;                                // 0..63
    const int j0   = jg * 2;
    const int b0   = lane & 1;          // which output this lane finalizes
    const bool writer = (lane & 10) == 0;  // bits 1,3 zero: 16 lanes/wave

    const float SC = 2.8853900817779268f;  // 2*log2(e)

    // ---- weights into registers (48 floats, prescaled), pinned ----
    v2f whh2[2][8];   // per jj: 16 floats of W_hh k-slice
    v2f wih2[2][4];   // per jj: 8 floats of W_ih k-slice
    float bs[2];
    #pragma unroll
    for (int jj = 0; jj < 2; ++jj) {
        const v2f* ph = (const v2f*)(W_hh + (j0 + jj) * HH + kg * 16);
        #pragma unroll
        for (int c = 0; c < 8; ++c) whh2[jj][c] = ph[c] * SC;
        const v2f* pi = (const v2f*)(W_ih + (j0 + jj) * XX + kg * 8);
        #pragma unroll
        for (int c = 0; c < 4; ++c) wih2[jj][c] = pi[c] * SC;
        bs[jj] = (b_ih[j0 + jj] + b_hh[j0 + jj]) * SC;
    }
    #pragma unroll
    for (int jj = 0; jj < 2; ++jj) {
        #pragma unroll
        for (int c = 0; c < 8; ++c) pin2(whh2[jj][c]);
        #pragma unroll
        for (int c = 0; c < 4; ++c) pin2(wih2[jj][c]);
    }
    const float bsel = b0 ? bs[1] : bs[0];

    // writer's output index and LDS slot
    const int jw   = j0 + b0;
    const int woff = (jw >> 4) * SSTR + (jw & 15);

    const float* xg = x + (size_t)b * TT * XX + kg * 8;

    if (tid < HBUF) h_lds[0][tid] = 0.f;

    v4f xa0 = ((const v4f*)xg)[0];
    v4f xa1 = ((const v4f*)xg)[1];
    v4f xb0 = ((const v4f*)(xg + XX))[0];
    v4f xb1 = ((const v4f*)(xg + XX))[1];
    __syncthreads();

#define STEP(RP, WP, X0, X1)                                              \
    do {                                                                  \
        const v4f* hp = (const v4f*)&h_lds[RP][kg * SSTR];                \
        const v4f H0 = hp[0], H1 = hp[1], H2 = hp[2], H3 = hp[3];         \
        const v2f h2[8] = { LO2(H0), HI2(H0), LO2(H1), HI2(H1),           \
                            LO2(H2), HI2(H2), LO2(H3), HI2(H3) };         \
        const v2f x2[4] = { LO2(X0), HI2(X0), LO2(X1), HI2(X1) };         \
        float s[2];                                                       \
        _Pragma("unroll")                                                 \
        for (int jj = 0; jj < 2; ++jj) {                                  \
            v2f a = {0.f, 0.f}, c = {0.f, 0.f};                           \
            PKFMA(a, wih2[jj][0], x2[0]); PKFMA(c, wih2[jj][1], x2[1]);   \
            PKFMA(a, wih2[jj][2], x2[2]); PKFMA(c, wih2[jj][3], x2[3]);   \
            PKFMA(a, whh2[jj][0], h2[0]); PKFMA(c, whh2[jj][1], h2[1]);   \
            PKFMA(a, whh2[jj][2], h2[2]); PKFMA(c, whh2[jj][3], h2[3]);   \
            PKFMA(a, whh2[jj][4], h2[4]); PKFMA(c, whh2[jj][5], h2[5]);   \
            PKFMA(a, whh2[jj][6], h2[6]); PKFMA(c, whh2[jj][7], h2[7]);   \
            a = a + c;                                                    \
            s[jj] = a.x + a.y;                                            \
        }                                                                 \
        /* reduce-scatter over kg: merge outputs on bit0, then xor2,xor8 */\
        float u = b0 ? s[1] : s[0];   /* kept output's partial */         \
        float v = b0 ? s[0] : s[1];   /* given to xor1 partner */         \
        u += dpp_mov<0xB1>(v);        /* quad_perm [1,0,3,2] = xor1 */    \
        u += dpp_mov<0x4E>(u);        /* quad_perm [2,3,0,1] = xor2 */    \
        u += dpp_mov<0x128>(u);       /* row_ror:8 = xor8 (dir-proof) */  \
        u += bsel;                    /* bias AFTER reduction (R3) */     \
        const float e  = __builtin_amdgcn_exp2f(u);                       \
        const float hn = fmaf(-2.f, __builtin_amdgcn_rcpf(e + 1.f), 1.f); \
        if (writer) h_lds[WP][woff] = hn;                                 \
        __syncthreads();                                                  \
    } while (0)

    for (int t = 0; t < TT; t += 2) {
        STEP(0, 1, xa0, xa1);
        {   // prefetch x for t+2 (consumed next even step)
            const int tn = (t + 2 < TT) ? t + 2 : TT - 1;
            const v4f* xp = (const v4f*)(xg + (size_t)tn * XX);
            xa0 = xp[0]; xa1 = xp[1];
        }
        STEP(1, 0, xb0, xb1);
        {   // prefetch x for t+3
            const int tn = (t + 3 < TT) ? t + 3 : TT - 1;
            const v4f* xp = (const v4f*)(xg + (size_t)tn * XX);
            xb0 = xp[0]; xb1 = xp[1];
        }
    }
#undef STEP

    // ---- readout: out[b, :] = h_last @ W_out^T + b_out (h in buffer 0) ----
    if (tid < YY) {
        const float* h  = h_lds[0];
        const float* wr = W_out + tid * HH;
        float r0 = 0.f, r1 = 0.f, r2 = 0.f, r3 = 0.f;
        #pragma unroll
        for (int s8 = 0; s8 < 8; ++s8) {   // 8 slices of 16 floats
            #pragma unroll
            for (int c = 0; c < 4; ++c) {
                const float4 wv = *(const float4*)(wr + s8 * 16 + c * 4);
                const float4 hv = *(const float4*)(h + s8 * SSTR + c * 4);
                r0 = fmaf(wv.x, hv.x, r0); r1 = fmaf(wv.y, hv.y, r1);
                r2 = fmaf(wv.z, hv.z, r2); r3 = fmaf(wv.w, hv.w, r3);
            }
        }
        out[b * YY + tid] = b_out[tid] + ((r0 + r1) + (r2 + r3));
    }
}

extern "C" void kernel_launch(void* const* d_in, const int* in_sizes, int n_in,
                              void* d_out, int out_size, void* d_ws, size_t ws_size,
                              hipStream_t stream) {
    const float* x     = (const float*)d_in[0];
    const float* W_ih  = (const float*)d_in[1];
    const float* W_hh  = (const float*)d_in[2];
    const float* b_ih  = (const float*)d_in[3];
    const float* b_hh  = (const float*)d_in[4];
    const float* W_out = (const float*)d_in[5];
    const float* b_out = (const float*)d_in[6];
    float* out = (float*)d_out;

    rnn_persist_kernel<<<BB, 512, 0, stream>>>(x, W_ih, W_hh, b_ih, b_hh,
                                               W_out, b_out, out);
}